// Round 1
// baseline (341.637 us; speedup 1.0000x reference)
//
#include <hip/hip_runtime.h>
#include <math.h>

#define SIGMA 0.248f
#define PP    7.5f
#define KK    3.0f
#define AL    2.5f

struct GW {
  float g1, g2;     // normalized Gaussian taps: g[±1], g[0] (outer taps ~7.5e-15 dropped)
  float w4[4];      // fused conv5+down2 per-axis taps, rows 2y-1..2y+2
  float omega[6];
};

// Fused up2x (bilinear, half-pixel, edge-clamped) + conv5 (zero-padded) per-axis weights.
// Output index y in [0,2n); contributing input rows are rb..rb+2 with weights wr[0..2].
__device__ __forceinline__ void build_w3(int y, int n, float g1, float g2,
                                         float* wr, int& rb) {
  int n2 = 2 * n;
  rb = (y >> 1) - 1;
  wr[0] = wr[1] = wr[2] = 0.f;
#pragma unroll
  for (int u = -1; u <= 1; ++u) {
    int Y = y + u;
    if (Y < 0 || Y >= n2) continue;   // conv zero-padding in upsampled domain
    float gw = (u == 0) ? g2 : g1;
    int m = Y >> 1;
    int r0, r1; float w0, w1;
    if (Y & 1) { r0 = m;     w0 = 0.75f; r1 = m + 1; w1 = 0.25f; }
    else       { r0 = m - 1; w0 = 0.25f; r1 = m;     w1 = 0.75f; }
    r0 = min(max(r0, 0), n - 1);      // bilinear edge clamp
    r1 = min(max(r1, 0), n - 1);
    wr[r0 - rb] += gw * w0;
    wr[r1 - rb] += gw * w1;
  }
}

// out[c,y,x] (h=n/2) = mean_{2x2} conv5(in)[2y+s,2x+t]  -- fused separable form
__global__ void down_k(const float* __restrict__ in, float* __restrict__ out,
                       int n, GW w) {
  int h = n >> 1;
  int x = blockIdx.x * blockDim.x + threadIdx.x;
  int y = blockIdx.y * blockDim.y + threadIdx.y;
  int c = blockIdx.z;
  if (x >= h || y >= h) return;
  const float* ip = in + (size_t)c * n * n;
  float acc = 0.f;
#pragma unroll
  for (int j = 0; j < 4; ++j) {
    int r = 2 * y - 1 + j;
    if (r < 0 || r >= n) continue;    // conv zero-padding
    const float* row = ip + (size_t)r * n;
    float racc = 0.f;
#pragma unroll
    for (int i = 0; i < 4; ++i) {
      int cc = 2 * x - 1 + i;
      if (cc < 0 || cc >= n) continue;
      racc += w.w4[i] * row[cc];
    }
    acc += w.w4[j] * racc;
  }
  out[((size_t)c * h + y) * h + x] = acc;
}

// out[c] (2n x 2n) = conv5(up2x(in[c]))
__global__ void upconv_k(const float* __restrict__ in, float* __restrict__ out,
                         int n, GW w) {
  int n2 = n * 2;
  int x = blockIdx.x * blockDim.x + threadIdx.x;
  int y = blockIdx.y * blockDim.y + threadIdx.y;
  int c = blockIdx.z;
  if (x >= n2 || y >= n2) return;
  float wr[3], wc[3]; int rb, cb;
  build_w3(y, n, w.g1, w.g2, wr, rb);
  build_w3(x, n, w.g1, w.g2, wc, cb);
  const float* ip = in + (size_t)c * n * n;
  float acc = 0.f;
#pragma unroll
  for (int j = 0; j < 3; ++j) {
    if (wr[j] == 0.f) continue;
    const float* row = ip + (size_t)(rb + j) * n;
    float racc = 0.f;
#pragma unroll
    for (int i = 0; i < 3; ++i) {
      if (wc[i] == 0.f) continue;
      racc += wc[i] * row[cb + i];
    }
    acc += wr[j] * racc;
  }
  out[((size_t)c * n2 + y) * n2 + x] = acc;
}

__device__ __forceinline__ float ts_f(float R, int idx) {
  // Ts[idx] = exp(-K * (2^(idx-2) * R / sigma)^2), idx in [0,4]
  float s = ldexpf(R, idx - 2) / SIGMA;
  return expf(-s * s * KK);
}

__global__ void blend_k(const float* __restrict__ img,
                        const float* __restrict__ C1, const float* __restrict__ C2,
                        const float* __restrict__ C3, const float* __restrict__ C4,
                        const float* __restrict__ C5,
                        const float* __restrict__ fixs, int nf,
                        float* __restrict__ out, GW w) {
  const int W = 2048, H = 2048, n = 1024;
  const size_t HW = (size_t)H * W;
  int x = blockIdx.x * blockDim.x + threadIdx.x;
  int y = blockIdx.y * blockDim.y + threadIdx.y;
  if (x >= W || y >= H) return;
  size_t pix = (size_t)y * W + x;

  // eccentricity -> R -> layer L
  float fxp = (float)x, fyp = (float)y;
  float d2 = 3.4e38f;
  for (int f = 0; f < nf; ++f) {
    float dx = fxp - fixs[2 * f];
    float dy = fyp - fixs[2 * f + 1];
    d2 = fminf(d2, dx * dx + dy * dy);
  }
  float theta = sqrtf(d2) / PP;
  float R = AL / (theta + AL);
  int L = 0;
#pragma unroll
  for (int i = 1; i <= 5; ++i)
    if (R >= w.omega[i] && R <= w.omega[i - 1]) L = i;

  if (L == 0) {  // pure As[0] = img
    out[pix]          = img[pix];
    out[HW + pix]     = img[HW + pix];
    out[2 * HW + pix] = img[2 * HW + pix];
    return;
  }

  float tsL   = (L == 5) ? 0.f : ts_f(R, L);
  float tsLm1 = ts_f(R, L - 1);
  float B = (0.5f - tsL) / (tsLm1 - tsL + 1e-5f);  // weight of As[L-1]
  float whi = 1.f - B;

  const float* Chi; const float* Clo;
  switch (L) {
    case 1: Chi = C1; Clo = nullptr; break;
    case 2: Chi = C2; Clo = C1; break;
    case 3: Chi = C3; Clo = C2; break;
    case 4: Chi = C4; Clo = C3; break;
    default: Chi = C5; Clo = C4; break;
  }

  float wr[3], wc[3]; int rb, cb;
  build_w3(y, n, w.g1, w.g2, wr, rb);
  build_w3(x, n, w.g1, w.g2, wc, cb);

  float hi0 = 0, hi1 = 0, hi2 = 0, lo0 = 0, lo1 = 0, lo2 = 0;
  const size_t nn = (size_t)n * n;
#pragma unroll
  for (int j = 0; j < 3; ++j) {
    if (wr[j] == 0.f) continue;
    size_t rowb = (size_t)(rb + j) * n;
#pragma unroll
    for (int i = 0; i < 3; ++i) {
      if (wc[i] == 0.f) continue;
      float ww = wr[j] * wc[i];
      size_t idx = rowb + (cb + i);
      hi0 += ww * Chi[idx];
      hi1 += ww * Chi[nn + idx];
      hi2 += ww * Chi[2 * nn + idx];
      if (Clo) {
        lo0 += ww * Clo[idx];
        lo1 += ww * Clo[nn + idx];
        lo2 += ww * Clo[2 * nn + idx];
      }
    }
  }
  if (L == 1) {  // As[0] = raw img, no blur
    lo0 = img[pix]; lo1 = img[HW + pix]; lo2 = img[2 * HW + pix];
  }
  out[pix]          = B * lo0 + whi * hi0;
  out[HW + pix]     = B * lo1 + whi * hi1;
  out[2 * HW + pix] = B * lo2 + whi * hi2;
}

extern "C" void kernel_launch(void* const* d_in, const int* in_sizes, int n_in,
                              void* d_out, int out_size, void* d_ws, size_t ws_size,
                              hipStream_t stream) {
  const float* img  = (const float*)d_in[0];
  const float* fixs = (const float*)d_in[1];
  int nf = in_sizes[1] / 2;
  float* out = (float*)d_out;
  float* ws  = (float*)d_ws;

  // ---- constants (double precision on host) ----
  GW w;
  double graw[5], S = 0.0;
  for (int d = -2; d <= 2; ++d) { graw[d + 2] = exp(-(double)(d * d) / (2.0 * 0.248 * 0.248)); S += graw[d + 2]; }
  double gn[5]; for (int i = 0; i < 5; ++i) gn[i] = graw[i] / S;
  w.g1 = (float)gn[1]; w.g2 = (float)gn[2];
  // fused down taps: g6[j] = 0.5*(g(j-2)+g(j-3)), keep j=1..4 (j=0,5 are ~3.8e-15)
  auto gat = [&](int d) -> double { return (d >= -2 && d <= 2) ? gn[d + 2] : 0.0; };
  for (int t = 0; t < 4; ++t) { int j = t + 1; w.w4[t] = (float)(0.5 * (gat(j - 2) + gat(j - 3))); }
  double ob = sqrt(log(2.0) / 3.0) * 0.248;
  double oms[6] = { ob * 4, ob * 2, ob, ob * 0.5, ob * 0.25, 0.0 };
  for (int i = 0; i < 6; ++i) w.omega[i] = (float)fmin(oms[i], 1.0);

  // ---- workspace carve-up (~73.4 MB) ----
  size_t o = 0;
  float* C1 = ws + o; o += 3ull * 1024 * 1024;   // = pyr[1]
  float* C2 = ws + o; o += 3ull * 1024 * 1024;
  float* C3 = ws + o; o += 3ull * 1024 * 1024;
  float* C4 = ws + o; o += 3ull * 1024 * 1024;
  float* C5 = ws + o; o += 3ull * 1024 * 1024;
  float* p2 = ws + o; o += 3ull * 512 * 512;
  float* p3 = ws + o; o += 3ull * 256 * 256;
  float* p4 = ws + o; o += 3ull * 128 * 128;
  float* p5 = ws + o; o += 3ull * 64 * 64;
  float* tA = ws + o; o += 3ull * 512 * 512;
  float* tB = ws + o; o += 3ull * 512 * 512;

  dim3 b16(16, 16, 1);
  auto g2d = [](int h) { return dim3((h + 15) / 16, (h + 15) / 16, 3); };

  // Gaussian pyramid (fused conv+down2)
  down_k<<<g2d(1024), b16, 0, stream>>>(img, C1, 2048, w);
  down_k<<<g2d(512),  b16, 0, stream>>>(C1,  p2, 1024, w);
  down_k<<<g2d(256),  b16, 0, stream>>>(p2,  p3, 512,  w);
  down_k<<<g2d(128),  b16, 0, stream>>>(p3,  p4, 256,  w);
  down_k<<<g2d(64),   b16, 0, stream>>>(p4,  p5, 128,  w);

  // Re-expansion chains, stopped at 1024^2 (final step fused into blend)
  upconv_k<<<g2d(1024), b16, 0, stream>>>(p2, C2, 512, w);

  upconv_k<<<g2d(512),  b16, 0, stream>>>(p3, tA, 256, w);
  upconv_k<<<g2d(1024), b16, 0, stream>>>(tA, C3, 512, w);

  upconv_k<<<g2d(256),  b16, 0, stream>>>(p4, tA, 128, w);
  upconv_k<<<g2d(512),  b16, 0, stream>>>(tA, tB, 256, w);
  upconv_k<<<g2d(1024), b16, 0, stream>>>(tB, C4, 512, w);

  upconv_k<<<g2d(128),  b16, 0, stream>>>(p5, tA, 64,  w);
  upconv_k<<<g2d(256),  b16, 0, stream>>>(tA, tB, 128, w);
  upconv_k<<<g2d(512),  b16, 0, stream>>>(tB, tA, 256, w);
  upconv_k<<<g2d(1024), b16, 0, stream>>>(tA, C5, 512, w);

  // Final blend: per-pixel picks levels L-1 and L, evaluates last up+conv on the fly
  dim3 bb(64, 4, 1), gb(2048 / 64, 2048 / 4, 1);
  blend_k<<<gb, bb, 0, stream>>>(img, C1, C2, C3, C4, C5, fixs, nf, out, w);
}

// Round 2
// 172.506 us; speedup vs baseline: 1.9804x; 1.9804x over previous
//
#include <hip/hip_runtime.h>
#include <math.h>

#define HW2048 (2048ull*2048ull)

struct BP {
  float P[4][3];   // composed 2-stage bilinear phase weights (exact, incl. clamped edges)
  float D2[5];     // d^2 thresholds: L = sum(d2 >= D2[j])
  float cc[5];     // Ts exponent coefs: ts_X = exp(-cc[X]*R^2)
};

struct UpB { const float* src[3]; float* dst[3]; };

// -------- pure 2x2 mean downsample (conv ~= identity at sigma=0.248) --------
__global__ void downmean_k(const float* __restrict__ in, float* __restrict__ out, int n) {
  int h = n >> 1;
  int x = blockIdx.x * blockDim.x + threadIdx.x;
  int y = blockIdx.y * blockDim.y + threadIdx.y;
  int c = blockIdx.z;
  if (x >= h || y >= h) return;
  const float* ip = in + (size_t)c * n * n + (size_t)(2 * y) * n + 2 * x;
  float2 a = *(const float2*)ip;
  float2 b = *(const float2*)(ip + n);
  out[((size_t)c * h + y) * h + x] = 0.25f * (a.x + a.y + b.x + b.y);
}

// -------- pure bilinear 2x upsample (half-pixel, edge clamp), batched --------
__global__ void up2_k(UpB u, int n) {
  int n2 = 2 * n;
  int x = blockIdx.x * blockDim.x + threadIdx.x;
  int y = blockIdx.y * blockDim.y + threadIdx.y;
  int z = blockIdx.z;
  if (x >= n2 || y >= n2) return;
  int im = z / 3, ch = z - im * 3;
  const float* ip = u.src[im] + (size_t)ch * n * n;
  int my = y >> 1, mx = x >> 1;
  int r0, r1, c0, c1; float wy0, wx0;
  if (y & 1) { r0 = my; r1 = min(my + 1, n - 1); wy0 = 0.75f; }
  else       { r0 = max(my - 1, 0); r1 = my;     wy0 = 0.25f; }
  if (x & 1) { c0 = mx; c1 = min(mx + 1, n - 1); wx0 = 0.75f; }
  else       { c0 = max(mx - 1, 0); c1 = mx;     wx0 = 0.25f; }
  float wy1 = 1.f - wy0, wx1 = 1.f - wx0;
  float v = wy0 * (wx0 * ip[(size_t)r0 * n + c0] + wx1 * ip[(size_t)r0 * n + c1])
          + wy1 * (wx0 * ip[(size_t)r1 * n + c0] + wx1 * ip[(size_t)r1 * n + c1]);
  u.dst[im][(size_t)ch * n2 * n2 + (size_t)y * n2 + x] = v;
}

// -------- blend helpers --------
__device__ __forceinline__ void phase_pair(const BP& bp, int parity, float wA[3], float wB[3]) {
#pragma unroll
  for (int t = 0; t < 3; ++t) {
    wA[t] = parity ? bp.P[2][t] : bp.P[0][t];
    wB[t] = parity ? bp.P[3][t] : bp.P[1][t];
  }
}

__device__ __forceinline__ void phase_one(const BP& bp, int ph, float w[3]) {
#pragma unroll
  for (int t = 0; t < 3; ++t)
    w[t] = (ph == 0) ? bp.P[0][t] : (ph == 1) ? bp.P[1][t] : (ph == 2) ? bp.P[2][t] : bp.P[3][t];
}

// sample level>=2 buffer (512^2) for a whole 2x2 output quad, all 3 channels
__device__ __forceinline__ void s2_quad(const float* __restrict__ buf, int qx, int qy,
                                        const BP& bp, float o[3][2][2]) {
  int ky = qy >> 1, kx = qx >> 1;
  float wr0[3], wr1[3], wc0[3], wc1[3];
  phase_pair(bp, qy & 1, wr0, wr1);
  phase_pair(bp, qx & 1, wc0, wc1);
  int r[3], c[3];
#pragma unroll
  for (int j = 0; j < 3; ++j) {
    r[j] = min(max(ky - 1 + j, 0), 511);
    c[j] = min(max(kx - 1 + j, 0), 511);
  }
#pragma unroll
  for (int ch = 0; ch < 3; ++ch) {
    const float* b = buf + ch * 262144;
    float cs0[3], cs1[3];
#pragma unroll
    for (int j = 0; j < 3; ++j) {
      const float* row = b + r[j] * 512;
      float w0 = row[c[0]], w1 = row[c[1]], w2 = row[c[2]];
      cs0[j] = wc0[0] * w0 + wc0[1] * w1 + wc0[2] * w2;
      cs1[j] = wc1[0] * w0 + wc1[1] * w1 + wc1[2] * w2;
    }
    o[ch][0][0] = wr0[0] * cs0[0] + wr0[1] * cs0[1] + wr0[2] * cs0[2];
    o[ch][0][1] = wr0[0] * cs1[0] + wr0[1] * cs1[1] + wr0[2] * cs1[2];
    o[ch][1][0] = wr1[0] * cs0[0] + wr1[1] * cs0[1] + wr1[2] * cs0[2];
    o[ch][1][1] = wr1[0] * cs1[0] + wr1[1] * cs1[1] + wr1[2] * cs1[2];
  }
}

// sample level 1 (C1, 1024^2, single bilinear stage) for a 2x2 quad
__device__ __forceinline__ void s1_quad(const float* __restrict__ C1, int qx, int qy,
                                        float o[3][2][2]) {
  int r[3], c[3];
#pragma unroll
  for (int j = 0; j < 3; ++j) {
    r[j] = min(max(qy - 1 + j, 0), 1023);
    c[j] = min(max(qx - 1 + j, 0), 1023);
  }
#pragma unroll
  for (int ch = 0; ch < 3; ++ch) {
    const float* b = C1 + ch * 1048576;
    float cs0[3], cs1[3];
#pragma unroll
    for (int j = 0; j < 3; ++j) {
      const float* row = b + r[j] * 1024;
      float w0 = row[c[0]], w1 = row[c[1]], w2 = row[c[2]];
      cs0[j] = 0.25f * w0 + 0.75f * w1;
      cs1[j] = 0.75f * w1 + 0.25f * w2;
    }
    o[ch][0][0] = 0.25f * cs0[0] + 0.75f * cs0[1];
    o[ch][0][1] = 0.25f * cs1[0] + 0.75f * cs1[1];
    o[ch][1][0] = 0.75f * cs0[1] + 0.25f * cs0[2];
    o[ch][1][1] = 0.75f * cs1[1] + 0.25f * cs1[2];
  }
}

__device__ __forceinline__ float calc_B(float dd, int L, const BP& bp) {
  float d = sqrtf(dd);
  float R = 18.75f / (d + 18.75f);       // P*ALPHA = 7.5*2.5
  float R2 = R * R;
  float cL = (L == 1) ? bp.cc[1] : (L == 2) ? bp.cc[2] : (L == 3) ? bp.cc[3] : bp.cc[4];
  float cm = (L == 1) ? bp.cc[0] : (L == 2) ? bp.cc[1] : (L == 3) ? bp.cc[2] : (L == 4) ? bp.cc[3] : bp.cc[4];
  float tsL = (L >= 5) ? 0.f : __expf(-cL * R2);
  float tsm = __expf(-cm * R2);
  return (0.5f - tsL) / (tsm - tsL + 1e-5f);
}

// per-pixel sampler for mixed-L quads (rare band-boundary ring)
__device__ void sample_px(int level, int x, int y,
                          const float* __restrict__ img, const float* __restrict__ C1,
                          const float* __restrict__ b2, const float* __restrict__ b3,
                          const float* __restrict__ b4, const float* __restrict__ b5,
                          const BP& bp, float v[3]) {
  if (level == 0) {
    size_t p = (size_t)y * 2048 + x;
    v[0] = img[p]; v[1] = img[p + HW2048]; v[2] = img[p + 2 * HW2048];
  } else if (level == 1) {
    int my = y >> 1, mx = x >> 1;
    int r0, r1, c0, c1; float wy0, wx0;
    if (y & 1) { r0 = my; r1 = min(my + 1, 1023); wy0 = 0.75f; }
    else       { r0 = max(my - 1, 0); r1 = my;    wy0 = 0.25f; }
    if (x & 1) { c0 = mx; c1 = min(mx + 1, 1023); wx0 = 0.75f; }
    else       { c0 = max(mx - 1, 0); c1 = mx;    wx0 = 0.25f; }
    float wy1 = 1.f - wy0, wx1 = 1.f - wx0;
#pragma unroll
    for (int ch = 0; ch < 3; ++ch) {
      const float* b = C1 + ch * 1048576;
      v[ch] = wy0 * (wx0 * b[r0 * 1024 + c0] + wx1 * b[r0 * 1024 + c1])
            + wy1 * (wx0 * b[r1 * 1024 + c0] + wx1 * b[r1 * 1024 + c1]);
    }
  } else {
    const float* buf = (level == 2) ? b2 : (level == 3) ? b3 : (level == 4) ? b4 : b5;
    int ky = y >> 2, kx = x >> 2;
    float wr[3], wc[3];
    phase_one(bp, y & 3, wr);
    phase_one(bp, x & 3, wc);
    int r[3], c[3];
#pragma unroll
    for (int j = 0; j < 3; ++j) {
      r[j] = min(max(ky - 1 + j, 0), 511);
      c[j] = min(max(kx - 1 + j, 0), 511);
    }
#pragma unroll
    for (int ch = 0; ch < 3; ++ch) {
      const float* b = buf + ch * 262144;
      float acc = 0.f;
#pragma unroll
      for (int j = 0; j < 3; ++j) {
        const float* row = b + r[j] * 512;
        acc += wr[j] * (wc[0] * row[c[0]] + wc[1] * row[c[1]] + wc[2] * row[c[2]]);
      }
      v[ch] = acc;
    }
  }
}

__global__ __launch_bounds__(256) void blend2_k(
    const float* __restrict__ img, const float* __restrict__ C1,
    const float* __restrict__ B2, const float* __restrict__ B3,
    const float* __restrict__ B4, const float* __restrict__ B5,
    const float* __restrict__ fixs, int nf, float* __restrict__ out, BP bp) {
  int qx = blockIdx.x * blockDim.x + threadIdx.x;   // quad coords, 0..1023
  int qy = blockIdx.y * blockDim.y + threadIdx.y;
  if (qx >= 1024 || qy >= 1024) return;
  float x0 = (float)(2 * qx), y0 = (float)(2 * qy);

  float d2[2][2] = {{3.4e38f, 3.4e38f}, {3.4e38f, 3.4e38f}};
  for (int f = 0; f < nf; ++f) {
    float dx = x0 - fixs[2 * f], dy = y0 - fixs[2 * f + 1];
#pragma unroll
    for (int sy = 0; sy < 2; ++sy)
#pragma unroll
      for (int sx = 0; sx < 2; ++sx) {
        float ddx = dx + (float)sx, ddy = dy + (float)sy;
        d2[sy][sx] = fminf(d2[sy][sx], ddx * ddx + ddy * ddy);
      }
  }

  int L[2][2], Lmin = 5, Lmax = 0;
#pragma unroll
  for (int sy = 0; sy < 2; ++sy)
#pragma unroll
    for (int sx = 0; sx < 2; ++sx) {
      float dd = d2[sy][sx];
      int l = (dd >= bp.D2[0]) + (dd >= bp.D2[1]) + (dd >= bp.D2[2]) +
              (dd >= bp.D2[3]) + (dd >= bp.D2[4]);
      L[sy][sx] = l;
      Lmin = min(Lmin, l); Lmax = max(Lmax, l);
    }

  size_t obase = (size_t)(2 * qy) * 2048 + 2 * qx;

  if (Lmax == 0) {  // pure As[0] = img
#pragma unroll
    for (int ch = 0; ch < 3; ++ch)
#pragma unroll
      for (int sy = 0; sy < 2; ++sy) {
        float2 v = *(const float2*)(img + (size_t)ch * HW2048 + obase + sy * 2048);
        *(float2*)(out + (size_t)ch * HW2048 + obase + sy * 2048) = v;
      }
    return;
  }

  if (Lmin == Lmax) {  // uniform-L quad: shared 3x3 tap window
    int Lu = Lmin;
    float Bv[2][2];
#pragma unroll
    for (int sy = 0; sy < 2; ++sy)
#pragma unroll
      for (int sx = 0; sx < 2; ++sx)
        Bv[sy][sx] = calc_B(d2[sy][sx], Lu, bp);

    float hi[3][2][2], lo[3][2][2];
    if (Lu == 1) {
      s1_quad(C1, qx, qy, hi);
#pragma unroll
      for (int ch = 0; ch < 3; ++ch)
#pragma unroll
        for (int sy = 0; sy < 2; ++sy) {
          float2 v = *(const float2*)(img + (size_t)ch * HW2048 + obase + sy * 2048);
          lo[ch][sy][0] = v.x; lo[ch][sy][1] = v.y;
        }
    } else {
      const float* hb = (Lu == 2) ? B2 : (Lu == 3) ? B3 : (Lu == 4) ? B4 : B5;
      s2_quad(hb, qx, qy, bp, hi);
      if (Lu == 2) s1_quad(C1, qx, qy, lo);
      else {
        const float* lb = (Lu == 3) ? B2 : (Lu == 4) ? B3 : B4;
        s2_quad(lb, qx, qy, bp, lo);
      }
    }
#pragma unroll
    for (int ch = 0; ch < 3; ++ch)
#pragma unroll
      for (int sy = 0; sy < 2; ++sy) {
        float2 r;
        r.x = Bv[sy][0] * lo[ch][sy][0] + (1.f - Bv[sy][0]) * hi[ch][sy][0];
        r.y = Bv[sy][1] * lo[ch][sy][1] + (1.f - Bv[sy][1]) * hi[ch][sy][1];
        *(float2*)(out + (size_t)ch * HW2048 + obase + sy * 2048) = r;
      }
    return;
  }

  // mixed-L quad: per-pixel general path
#pragma unroll
  for (int sy = 0; sy < 2; ++sy)
#pragma unroll
    for (int sx = 0; sx < 2; ++sx) {
      int l = L[sy][sx];
      size_t p = obase + sy * 2048 + sx;
      float vo[3];
      if (l == 0) {
        vo[0] = img[p]; vo[1] = img[p + HW2048]; vo[2] = img[p + 2 * HW2048];
      } else {
        float B = calc_B(d2[sy][sx], l, bp);
        float hi[3], lo[3];
        sample_px(l,     2 * qx + sx, 2 * qy + sy, img, C1, B2, B3, B4, B5, bp, hi);
        sample_px(l - 1, 2 * qx + sx, 2 * qy + sy, img, C1, B2, B3, B4, B5, bp, lo);
#pragma unroll
        for (int ch = 0; ch < 3; ++ch) vo[ch] = B * lo[ch] + (1.f - B) * hi[ch];
      }
      out[p] = vo[0]; out[p + HW2048] = vo[1]; out[p + 2 * HW2048] = vo[2];
    }
}

extern "C" void kernel_launch(void* const* d_in, const int* in_sizes, int n_in,
                              void* d_out, int out_size, void* d_ws, size_t ws_size,
                              hipStream_t stream) {
  const float* img  = (const float*)d_in[0];
  const float* fixs = (const float*)d_in[1];
  int nf = in_sizes[1] / 2;
  float* out = (float*)d_out;
  float* ws  = (float*)d_ws;

  // ---- constants ----
  BP bp;
  const double sig = 0.248, Kd = 3.0, Pd = 7.5, Ad = 2.5;
  double ob = sqrt(log(2.0) / Kd) * sig;
  for (int j = 0; j < 5; ++j) {
    double om = ob * pow(2.0, 2 - j);           // omega[j] (all < 1)
    double Dj = Pd * Ad * (1.0 / om - 1.0);     // d threshold for R <= omega[j]
    bp.D2[j] = (float)(Dj * Dj);
  }
  for (int X = 0; X < 5; ++X)
    bp.cc[X] = (float)(Kd * pow(2.0, 2.0 * (X - 2)) / (sig * sig));
  const float Pt[4][3] = {{0.375f, 0.625f, 0.f},
                          {0.1875f, 0.75f, 0.0625f},
                          {0.0625f, 0.75f, 0.1875f},
                          {0.f, 0.625f, 0.375f}};
  for (int a = 0; a < 4; ++a) for (int t = 0; t < 3; ++t) bp.P[a][t] = Pt[a][t];

  // ---- workspace (~28 MB) ----
  size_t o = 0;
  float* C1 = ws + o; o += 3ull * 1024 * 1024;   // pyr[1]
  float* p2 = ws + o; o += 3ull * 512 * 512;     // pyr[2] == level-2 blend source
  float* p3 = ws + o; o += 3ull * 256 * 256;
  float* p4 = ws + o; o += 3ull * 128 * 128;
  float* p5 = ws + o; o += 3ull * 64 * 64;
  float* U3 = ws + o; o += 3ull * 512 * 512;     // up(p3)
  float* U4 = ws + o; o += 3ull * 512 * 512;     // up^2(p4)
  float* U5 = ws + o; o += 3ull * 512 * 512;     // up^3(p5)
  float* tA = ws + o; o += 3ull * 128 * 128;
  float* tB = ws + o; o += 3ull * 256 * 256;
  float* tC = ws + o; o += 3ull * 256 * 256;

  dim3 b(64, 4, 1);
  auto grd = [](int w, int h, int z) { return dim3((w + 63) / 64, (h + 3) / 4, z); };

  // pyramid (pure 2x2 mean)
  downmean_k<<<grd(1024, 1024, 3), b, 0, stream>>>(img, C1, 2048);
  downmean_k<<<grd(512, 512, 3),   b, 0, stream>>>(C1, p2, 1024);
  downmean_k<<<grd(256, 256, 3),   b, 0, stream>>>(p2, p3, 512);
  downmean_k<<<grd(128, 128, 3),   b, 0, stream>>>(p3, p4, 256);
  downmean_k<<<grd(64, 64, 3),     b, 0, stream>>>(p4, p5, 128);

  // re-expansion to 512^2 only (last two stages fused into blend), batched by size
  UpB uA{}; uA.src[0] = p5; uA.dst[0] = tA;
  up2_k<<<grd(128, 128, 3), b, 0, stream>>>(uA, 64);
  UpB uB{}; uB.src[0] = tA; uB.dst[0] = tB; uB.src[1] = p4; uB.dst[1] = tC;
  up2_k<<<grd(256, 256, 6), b, 0, stream>>>(uB, 128);
  UpB uC{}; uC.src[0] = tB; uC.dst[0] = U5; uC.src[1] = tC; uC.dst[1] = U4;
  uC.src[2] = p3; uC.dst[2] = U3;
  up2_k<<<grd(512, 512, 9), b, 0, stream>>>(uC, 256);

  // blend: per-quad, fused final 2-stage (or 1-stage) upsample on the fly
  blend2_k<<<dim3(16, 256, 1), b, 0, stream>>>(img, C1, p2, U3, U4, U5, fixs, nf, out, bp);
}

// Round 3
// 162.226 us; speedup vs baseline: 2.1059x; 1.0634x over previous
//
#include <hip/hip_runtime.h>
#include <math.h>

#define HW2048 (2048ull*2048ull)
typedef float f4 __attribute__((ext_vector_type(4)));

struct BP {
  float P[4][3];   // composed 2-stage bilinear phase weights
  float D2[5];     // d^2 thresholds: L = sum(d2 >= D2[j])
  float cc[5];     // Ts exponent coefs
};

// ---------------- K1: img -> C1 (1024^2) + p2 (512^2), fused 2x 2x2-mean ----
__global__ __launch_bounds__(256) void down12_k(const float* __restrict__ img,
                                                float* __restrict__ C1,
                                                float* __restrict__ p2) {
  __shared__ float t[32][33];
  int tx = threadIdx.x, ty = threadIdx.y;        // block (16,16)
  int bx = blockIdx.x, by = blockIdx.y, c = blockIdx.z;
  const float* ip = img + (size_t)c * HW2048;
#pragma unroll
  for (int sy = 0; sy < 2; ++sy)
#pragma unroll
    for (int sx = 0; sx < 2; ++sx) {
      int lx = tx + 16 * sx, ly = ty + 16 * sy;
      int gx = bx * 32 + lx, gy = by * 32 + ly;
      const float* p = ip + (size_t)(2 * gy) * 2048 + 2 * gx;
      float2 a = *(const float2*)p;
      float2 bq = *(const float2*)(p + 2048);
      float v = 0.25f * (a.x + a.y + bq.x + bq.y);
      t[ly][lx] = v;
      C1[((size_t)c * 1024 + gy) * 1024 + gx] = v;
    }
  __syncthreads();
  float v = 0.25f * (t[2*ty][2*tx] + t[2*ty][2*tx+1] + t[2*ty+1][2*tx] + t[2*ty+1][2*tx+1]);
  p2[((size_t)c * 512 + by * 16 + ty) * 512 + bx * 16 + tx] = v;
}

// ---------------- K2: p2 -> p3 + p4 + p5, fused 3x 2x2-mean ------------------
__global__ __launch_bounds__(256) void down345_k(const float* __restrict__ p2,
                                                 float* __restrict__ p3,
                                                 float* __restrict__ p4,
                                                 float* __restrict__ p5) {
  __shared__ float t3[32][33];
  __shared__ float t4[16][17];
  int tx = threadIdx.x, ty = threadIdx.y;        // (16,16); grid (8,8,3)
  int bx = blockIdx.x, by = blockIdx.y, c = blockIdx.z;
  const float* ip = p2 + (size_t)c * 512 * 512;
#pragma unroll
  for (int sy = 0; sy < 2; ++sy)
#pragma unroll
    for (int sx = 0; sx < 2; ++sx) {
      int lx = tx + 16 * sx, ly = ty + 16 * sy;
      int gx = bx * 32 + lx, gy = by * 32 + ly;
      const float* p = ip + (size_t)(2 * gy) * 512 + 2 * gx;
      float2 a = *(const float2*)p;
      float2 bq = *(const float2*)(p + 512);
      float v = 0.25f * (a.x + a.y + bq.x + bq.y);
      t3[ly][lx] = v;
      p3[((size_t)c * 256 + gy) * 256 + gx] = v;
    }
  __syncthreads();
  {
    float v = 0.25f * (t3[2*ty][2*tx] + t3[2*ty][2*tx+1] + t3[2*ty+1][2*tx] + t3[2*ty+1][2*tx+1]);
    t4[ty][tx] = v;
    p4[((size_t)c * 128 + by * 16 + ty) * 128 + bx * 16 + tx] = v;
  }
  __syncthreads();
  int tid = ty * 16 + tx;
  if (tid < 64) {
    int y = tid >> 3, x = tid & 7;
    float v = 0.25f * (t4[2*y][2*x] + t4[2*y][2*x+1] + t4[2*y+1][2*x] + t4[2*y+1][2*x+1]);
    p5[((size_t)c * 64 + by * 8 + y) * 64 + bx * 8 + x] = v;
  }
}

// ---------------- K3: fused up-chains p3->U3, p4->U4, p5->U5 (all 512^2) -----
__device__ __forceinline__ void up_coords(int o, int n, int& i0, int& i1, float& w0) {
  int m = o >> 1;
  if (o & 1) { i0 = m; i1 = min(m + 1, n - 1); w0 = 0.75f; }
  else       { i0 = max(m - 1, 0); i1 = m;     w0 = 0.25f; }
}

__global__ __launch_bounds__(256) void upchain_k(const float* __restrict__ p3,
                                                 const float* __restrict__ p4,
                                                 const float* __restrict__ p5,
                                                 float* __restrict__ U3,
                                                 float* __restrict__ U4,
                                                 float* __restrict__ U5) {
  __shared__ float a[19][20];     // 128-level window (U5 chain)
  __shared__ float mid[34][35];   // 256-level window (U4/U5 chains)
  int z = blockIdx.z, im = z / 3, ch = z - im * 3;   // grid (8,8,9)
  int X0 = blockIdx.x * 64, Y0 = blockIdx.y * 64;
  int tid = threadIdx.x;          // 256 threads
  int bx1 = X0 / 4 - 1, by1 = Y0 / 4 - 1;
  int bx2 = X0 / 2 - 1, by2 = Y0 / 2 - 1;

  if (im == 2) {
    const float* s = p5 + ch * 64 * 64;
    for (int j = tid; j < 18 * 18; j += 256) {
      int r = j / 18, cc = j % 18;
      int gy = min(max(by1 + r, 0), 127), gx = min(max(bx1 + cc, 0), 127);
      int r0, r1, c0, c1; float wy0, wx0;
      up_coords(gy, 64, r0, r1, wy0);
      up_coords(gx, 64, c0, c1, wx0);
      float wy1 = 1.f - wy0, wx1 = 1.f - wx0;
      a[r][cc] = wy0 * (wx0 * s[r0*64+c0] + wx1 * s[r0*64+c1])
               + wy1 * (wx0 * s[r1*64+c0] + wx1 * s[r1*64+c1]);
    }
    __syncthreads();
    for (int j = tid; j < 34 * 34; j += 256) {
      int r = j / 34, cc = j % 34;
      int gy = min(max(by2 + r, 0), 255), gx = min(max(bx2 + cc, 0), 255);
      int r0, r1, c0, c1; float wy0, wx0;
      up_coords(gy, 128, r0, r1, wy0);
      up_coords(gx, 128, c0, c1, wx0);
      float wy1 = 1.f - wy0, wx1 = 1.f - wx0;
      int a0 = r0 - by1, a1 = r1 - by1, b0 = c0 - bx1, b1 = c1 - bx1;
      mid[r][cc] = wy0 * (wx0 * a[a0][b0] + wx1 * a[a0][b1])
                 + wy1 * (wx0 * a[a1][b0] + wx1 * a[a1][b1]);
    }
    __syncthreads();
  } else if (im == 1) {
    const float* s = p4 + ch * 128 * 128;
    for (int j = tid; j < 34 * 34; j += 256) {
      int r = j / 34, cc = j % 34;
      int gy = min(max(by2 + r, 0), 255), gx = min(max(bx2 + cc, 0), 255);
      int r0, r1, c0, c1; float wy0, wx0;
      up_coords(gy, 128, r0, r1, wy0);
      up_coords(gx, 128, c0, c1, wx0);
      float wy1 = 1.f - wy0, wx1 = 1.f - wx0;
      mid[r][cc] = wy0 * (wx0 * s[r0*128+c0] + wx1 * s[r0*128+c1])
                 + wy1 * (wx0 * s[r1*128+c0] + wx1 * s[r1*128+c1]);
    }
    __syncthreads();
  }

  float* dst = (im == 0) ? U3 : (im == 1) ? U4 : U5;
  const float* p3g = p3 + ch * 256 * 256;
  int lx = tid & 63, lyb = tid >> 6;
#pragma unroll 4
  for (int rr = 0; rr < 16; ++rr) {
    int ly = lyb * 16 + rr;
    int x = X0 + lx, y = Y0 + ly;
    int r0, r1, c0, c1; float wy0, wx0;
    up_coords(y, 256, r0, r1, wy0);
    up_coords(x, 256, c0, c1, wx0);
    float wy1 = 1.f - wy0, wx1 = 1.f - wx0;
    float v;
    if (im == 0) {
      v = wy0 * (wx0 * p3g[r0*256+c0] + wx1 * p3g[r0*256+c1])
        + wy1 * (wx0 * p3g[r1*256+c0] + wx1 * p3g[r1*256+c1]);
    } else {
      int a0 = r0 - by2, a1 = r1 - by2, b0 = c0 - bx2, b1 = c1 - bx2;
      v = wy0 * (wx0 * mid[a0][b0] + wx1 * mid[a0][b1])
        + wy1 * (wx0 * mid[a1][b0] + wx1 * mid[a1][b1]);
    }
    dst[((size_t)ch * 512 + y) * 512 + x] = v;
  }
}

// ---------------- blend helpers ---------------------------------------------
__device__ __forceinline__ void phase_one(const BP& bp, int ph, float w[3]) {
#pragma unroll
  for (int t = 0; t < 3; ++t)
    w[t] = (ph == 0) ? bp.P[0][t] : (ph == 1) ? bp.P[1][t] : (ph == 2) ? bp.P[2][t] : bp.P[3][t];
}

__device__ __forceinline__ float calc_B(float dd, int L, const BP& bp) {
  float d = sqrtf(dd);
  float R = 18.75f / (d + 18.75f);
  float R2 = R * R;
  float cL = (L == 1) ? bp.cc[1] : (L == 2) ? bp.cc[2] : (L == 3) ? bp.cc[3] : bp.cc[4];
  float cm = (L == 1) ? bp.cc[0] : (L == 2) ? bp.cc[1] : (L == 3) ? bp.cc[2] : (L == 4) ? bp.cc[3] : bp.cc[4];
  float tsL = (L >= 5) ? 0.f : __expf(-cL * R2);
  float tsm = __expf(-cm * R2);
  return (0.5f - tsL) / (tsm - tsL + 1e-5f);
}

// sample a 512^2 buffer for a 4x2 output span (x0 mult of 4, y0 mult of 2)
__device__ __forceinline__ void s2_span(const float* __restrict__ buf, int x0, int y0,
                                        const BP& bp, float o[3][2][4]) {
  int t = x0 >> 2, ky = y0 >> 2, yph = y0 & 3;  // yph in {0,2}
  int c[3], r[3];
#pragma unroll
  for (int j = 0; j < 3; ++j) {
    c[j] = min(max(t - 1 + j, 0), 511);
    r[j] = min(max(ky - 1 + j, 0), 511);
  }
  const float* wr0 = bp.P[yph];
  const float* wr1 = bp.P[yph + 1];
#pragma unroll
  for (int ch = 0; ch < 3; ++ch) {
    const float* b = buf + ch * 262144;
    float v[3][3];
#pragma unroll
    for (int j = 0; j < 3; ++j) {
      const float* row = b + r[j] * 512;
      v[j][0] = row[c[0]]; v[j][1] = row[c[1]]; v[j][2] = row[c[2]];
    }
    float rv0[3], rv1[3];
#pragma unroll
    for (int i = 0; i < 3; ++i) {
      rv0[i] = wr0[0] * v[0][i] + wr0[1] * v[1][i] + wr0[2] * v[2][i];
      rv1[i] = wr1[0] * v[0][i] + wr1[1] * v[1][i] + wr1[2] * v[2][i];
    }
#pragma unroll
    for (int p = 0; p < 4; ++p) {
      o[ch][0][p] = bp.P[p][0] * rv0[0] + bp.P[p][1] * rv0[1] + bp.P[p][2] * rv0[2];
      o[ch][1][p] = bp.P[p][0] * rv1[0] + bp.P[p][1] * rv1[1] + bp.P[p][2] * rv1[2];
    }
  }
}

// sample C1 (1024^2, single bilinear stage) for a 4x2 output span
__device__ __forceinline__ void s1_span(const float* __restrict__ C1, int x0, int y0,
                                        float o[3][2][4]) {
  int q0 = x0 >> 1, qy = y0 >> 1;
  int c[4], r[3];
#pragma unroll
  for (int i = 0; i < 4; ++i) c[i] = min(max(q0 - 1 + i, 0), 1023);
#pragma unroll
  for (int j = 0; j < 3; ++j) r[j] = min(max(qy - 1 + j, 0), 1023);
#pragma unroll
  for (int ch = 0; ch < 3; ++ch) {
    const float* b = C1 + ch * 1048576;
    float v[3][4];
#pragma unroll
    for (int j = 0; j < 3; ++j) {
      const float* row = b + r[j] * 1024;
      v[j][0] = row[c[0]]; v[j][1] = row[c[1]]; v[j][2] = row[c[2]]; v[j][3] = row[c[3]];
    }
    float rv0[4], rv1[4];
#pragma unroll
    for (int i = 0; i < 4; ++i) {
      rv0[i] = 0.25f * v[0][i] + 0.75f * v[1][i];
      rv1[i] = 0.75f * v[1][i] + 0.25f * v[2][i];
    }
    o[ch][0][0] = 0.25f * rv0[0] + 0.75f * rv0[1];
    o[ch][0][1] = 0.75f * rv0[1] + 0.25f * rv0[2];
    o[ch][0][2] = 0.25f * rv0[1] + 0.75f * rv0[2];
    o[ch][0][3] = 0.75f * rv0[2] + 0.25f * rv0[3];
    o[ch][1][0] = 0.25f * rv1[0] + 0.75f * rv1[1];
    o[ch][1][1] = 0.75f * rv1[1] + 0.25f * rv1[2];
    o[ch][1][2] = 0.25f * rv1[1] + 0.75f * rv1[2];
    o[ch][1][3] = 0.75f * rv1[2] + 0.25f * rv1[3];
  }
}

// per-pixel sampler for mixed-L spans
__device__ void sample_px(int level, int x, int y,
                          const float* __restrict__ img, const float* __restrict__ C1,
                          const float* __restrict__ b2, const float* __restrict__ b3,
                          const float* __restrict__ b4, const float* __restrict__ b5,
                          const BP& bp, float v[3]) {
  if (level == 0) {
    size_t p = (size_t)y * 2048 + x;
    v[0] = img[p]; v[1] = img[p + HW2048]; v[2] = img[p + 2 * HW2048];
  } else if (level == 1) {
    int my = y >> 1, mx = x >> 1;
    int r0, r1, c0, c1; float wy0, wx0;
    up_coords(y, 1024, r0, r1, wy0);
    up_coords(x, 1024, c0, c1, wx0);
    (void)my; (void)mx;
    float wy1 = 1.f - wy0, wx1 = 1.f - wx0;
#pragma unroll
    for (int ch = 0; ch < 3; ++ch) {
      const float* b = C1 + ch * 1048576;
      v[ch] = wy0 * (wx0 * b[r0 * 1024 + c0] + wx1 * b[r0 * 1024 + c1])
            + wy1 * (wx0 * b[r1 * 1024 + c0] + wx1 * b[r1 * 1024 + c1]);
    }
  } else {
    const float* buf = (level == 2) ? b2 : (level == 3) ? b3 : (level == 4) ? b4 : b5;
    int ky = y >> 2, kx = x >> 2;
    float wr[3], wc[3];
    phase_one(bp, y & 3, wr);
    phase_one(bp, x & 3, wc);
    int r[3], c[3];
#pragma unroll
    for (int j = 0; j < 3; ++j) {
      r[j] = min(max(ky - 1 + j, 0), 511);
      c[j] = min(max(kx - 1 + j, 0), 511);
    }
#pragma unroll
    for (int ch = 0; ch < 3; ++ch) {
      const float* b = buf + ch * 262144;
      float acc = 0.f;
#pragma unroll
      for (int j = 0; j < 3; ++j) {
        const float* row = b + r[j] * 512;
        acc += wr[j] * (wc[0] * row[c[0]] + wc[1] * row[c[1]] + wc[2] * row[c[2]]);
      }
      v[ch] = acc;
    }
  }
}

// ---------------- K4: blend, 4x2 px per thread ------------------------------
__global__ __launch_bounds__(256) void blend3_k(
    const float* __restrict__ img, const float* __restrict__ C1,
    const float* __restrict__ B2, const float* __restrict__ B3,
    const float* __restrict__ B4, const float* __restrict__ B5,
    const float* __restrict__ fixs, int nf, float* __restrict__ out, BP bp) {
  int tx = threadIdx.x, ty = threadIdx.y;        // (64,4); grid (8,256)
  int x0 = (blockIdx.x * 64 + tx) * 4;
  int y0 = (blockIdx.y * 4 + ty) * 2;
  size_t ob = (size_t)y0 * 2048 + x0;

  float d2[2][4];
#pragma unroll
  for (int j = 0; j < 2; ++j)
#pragma unroll
    for (int i = 0; i < 4; ++i) d2[j][i] = 3.4e38f;
  for (int f = 0; f < nf; ++f) {
    float dx0 = (float)x0 - fixs[2 * f], dy0 = (float)y0 - fixs[2 * f + 1];
#pragma unroll
    for (int j = 0; j < 2; ++j) {
      float dy = dy0 + (float)j, dy2 = dy * dy;
#pragma unroll
      for (int i = 0; i < 4; ++i) {
        float dx = dx0 + (float)i;
        d2[j][i] = fminf(d2[j][i], dx * dx + dy2);
      }
    }
  }

  int L[2][4], Lmin = 5, Lmax = 0;
#pragma unroll
  for (int j = 0; j < 2; ++j)
#pragma unroll
    for (int i = 0; i < 4; ++i) {
      float dd = d2[j][i];
      int l = (dd >= bp.D2[0]) + (dd >= bp.D2[1]) + (dd >= bp.D2[2]) +
              (dd >= bp.D2[3]) + (dd >= bp.D2[4]);
      L[j][i] = l;
      Lmin = min(Lmin, l); Lmax = max(Lmax, l);
    }

  float res[3][2][4];

  if (Lmax == 0) {
#pragma unroll
    for (int ch = 0; ch < 3; ++ch)
#pragma unroll
      for (int j = 0; j < 2; ++j) {
        f4 v = *(const f4*)(img + (size_t)ch * HW2048 + ob + (size_t)j * 2048);
        res[ch][j][0] = v.x; res[ch][j][1] = v.y; res[ch][j][2] = v.z; res[ch][j][3] = v.w;
      }
  } else if (Lmin == Lmax) {
    int Lu = Lmin;
    float Bv[2][4];
#pragma unroll
    for (int j = 0; j < 2; ++j)
#pragma unroll
      for (int i = 0; i < 4; ++i) Bv[j][i] = calc_B(d2[j][i], Lu, bp);

    float hi[3][2][4], lo[3][2][4];
    if (Lu == 1) {
      s1_span(C1, x0, y0, hi);
#pragma unroll
      for (int ch = 0; ch < 3; ++ch)
#pragma unroll
        for (int j = 0; j < 2; ++j) {
          f4 v = *(const f4*)(img + (size_t)ch * HW2048 + ob + (size_t)j * 2048);
          lo[ch][j][0] = v.x; lo[ch][j][1] = v.y; lo[ch][j][2] = v.z; lo[ch][j][3] = v.w;
        }
    } else {
      const float* hb = (Lu == 2) ? B2 : (Lu == 3) ? B3 : (Lu == 4) ? B4 : B5;
      s2_span(hb, x0, y0, bp, hi);
      if (Lu == 2) s1_span(C1, x0, y0, lo);
      else {
        const float* lb = (Lu == 3) ? B2 : (Lu == 4) ? B3 : B4;
        s2_span(lb, x0, y0, bp, lo);
      }
    }
#pragma unroll
    for (int ch = 0; ch < 3; ++ch)
#pragma unroll
      for (int j = 0; j < 2; ++j)
#pragma unroll
        for (int i = 0; i < 4; ++i)
          res[ch][j][i] = Bv[j][i] * lo[ch][j][i] + (1.f - Bv[j][i]) * hi[ch][j][i];
  } else {
    // mixed-L span: per-pixel general path
#pragma unroll
    for (int j = 0; j < 2; ++j)
#pragma unroll
      for (int i = 0; i < 4; ++i) {
        int l = L[j][i];
        int px = x0 + i, py = y0 + j;
        if (l == 0) {
          size_t p = (size_t)py * 2048 + px;
          res[0][j][i] = img[p]; res[1][j][i] = img[p + HW2048]; res[2][j][i] = img[p + 2 * HW2048];
        } else {
          float B = calc_B(d2[j][i], l, bp);
          float hi[3], lo[3];
          sample_px(l,     px, py, img, C1, B2, B3, B4, B5, bp, hi);
          sample_px(l - 1, px, py, img, C1, B2, B3, B4, B5, bp, lo);
#pragma unroll
          for (int ch = 0; ch < 3; ++ch) res[ch][j][i] = B * lo[ch] + (1.f - B) * hi[ch];
        }
      }
  }

#pragma unroll
  for (int ch = 0; ch < 3; ++ch)
#pragma unroll
    for (int j = 0; j < 2; ++j) {
      f4 v;
      v.x = res[ch][j][0]; v.y = res[ch][j][1]; v.z = res[ch][j][2]; v.w = res[ch][j][3];
      __builtin_nontemporal_store(v, (f4*)(out + (size_t)ch * HW2048 + ob + (size_t)j * 2048));
    }
}

extern "C" void kernel_launch(void* const* d_in, const int* in_sizes, int n_in,
                              void* d_out, int out_size, void* d_ws, size_t ws_size,
                              hipStream_t stream) {
  const float* img  = (const float*)d_in[0];
  const float* fixs = (const float*)d_in[1];
  int nf = in_sizes[1] / 2;
  float* out = (float*)d_out;
  float* ws  = (float*)d_ws;

  BP bp;
  const double sig = 0.248, Kd = 3.0, Pd = 7.5, Ad = 2.5;
  double obv = sqrt(log(2.0) / Kd) * sig;
  for (int j = 0; j < 5; ++j) {
    double om = obv * pow(2.0, 2 - j);
    double Dj = Pd * Ad * (1.0 / om - 1.0);
    bp.D2[j] = (float)(Dj * Dj);
  }
  for (int X = 0; X < 5; ++X)
    bp.cc[X] = (float)(Kd * pow(2.0, 2.0 * (X - 2)) / (sig * sig));
  const float Pt[4][3] = {{0.375f, 0.625f, 0.f},
                          {0.1875f, 0.75f, 0.0625f},
                          {0.0625f, 0.75f, 0.1875f},
                          {0.f, 0.625f, 0.375f}};
  for (int a = 0; a < 4; ++a) for (int t = 0; t < 3; ++t) bp.P[a][t] = Pt[a][t];

  size_t o = 0;
  float* C1 = ws + o; o += 3ull * 1024 * 1024;
  float* p2 = ws + o; o += 3ull * 512 * 512;
  float* p3 = ws + o; o += 3ull * 256 * 256;
  float* p4 = ws + o; o += 3ull * 128 * 128;
  float* p5 = ws + o; o += 3ull * 64 * 64;
  float* U3 = ws + o; o += 3ull * 512 * 512;
  float* U4 = ws + o; o += 3ull * 512 * 512;
  float* U5 = ws + o; o += 3ull * 512 * 512;

  down12_k <<<dim3(32, 32, 3), dim3(16, 16), 0, stream>>>(img, C1, p2);
  down345_k<<<dim3(8, 8, 3),   dim3(16, 16), 0, stream>>>(p2, p3, p4, p5);
  upchain_k<<<dim3(8, 8, 9),   dim3(256),    0, stream>>>(p3, p4, p5, U3, U4, U5);
  blend3_k <<<dim3(8, 256),    dim3(64, 4),  0, stream>>>(img, C1, p2, U3, U4, U5,
                                                          fixs, nf, out, bp);
}

// Round 4
// 158.376 us; speedup vs baseline: 2.1571x; 1.0243x over previous
//
#include <hip/hip_runtime.h>
#include <math.h>

#define HW2048 (2048ull*2048ull)
typedef float f4 __attribute__((ext_vector_type(4)));
typedef float f2 __attribute__((ext_vector_type(2)));
typedef _Float16 h8 __attribute__((ext_vector_type(8)));   // 16 B

struct BP {
  float P[4][3];   // composed 2-stage bilinear phase weights
  float D2[5];     // d^2 thresholds: L = sum(d2 >= D2[j])
  float cc[5];     // Ts exponent coefs
};

// ---------------- K1: img -> C1 (1024^2) + p2 (512^2), no LDS ---------------
__global__ __launch_bounds__(256) void down12_k(const float* __restrict__ img,
                                                float* __restrict__ C1,
                                                float* __restrict__ p2) {
  int X = blockIdx.x * 16 + threadIdx.x;   // 0..511
  int Y = blockIdx.y * 16 + threadIdx.y;   // 0..511
  int c = blockIdx.z;
  const float* ip = img + (size_t)c * HW2048 + (size_t)(4 * Y) * 2048 + 4 * X;
  f4 r0 = __builtin_nontemporal_load((const f4*)(ip));
  f4 r1 = __builtin_nontemporal_load((const f4*)(ip + 2048));
  f4 r2 = __builtin_nontemporal_load((const f4*)(ip + 4096));
  f4 r3 = __builtin_nontemporal_load((const f4*)(ip + 6144));
  float a00 = 0.25f * (r0.x + r0.y + r1.x + r1.y);
  float a01 = 0.25f * (r0.z + r0.w + r1.z + r1.w);
  float a10 = 0.25f * (r2.x + r2.y + r3.x + r3.y);
  float a11 = 0.25f * (r2.z + r2.w + r3.z + r3.w);
  float* cp = C1 + (size_t)c * 1048576 + (size_t)(2 * Y) * 1024 + 2 * X;
  f2 u; u.x = a00; u.y = a01; *(f2*)cp = u;
  f2 v; v.x = a10; v.y = a11; *(f2*)(cp + 1024) = v;
  p2[((size_t)c * 512 + Y) * 512 + X] = 0.25f * (a00 + a01 + a10 + a11);
}

// ---------------- K2: p2 -> p3 + p4 + p5 ------------------------------------
__global__ __launch_bounds__(256) void down345_k(const float* __restrict__ p2,
                                                 float* __restrict__ p3,
                                                 float* __restrict__ p4,
                                                 float* __restrict__ p5) {
  __shared__ float t4[16][17];
  int tx = threadIdx.x, ty = threadIdx.y;          // (16,16); grid (8,8,3)
  int X = blockIdx.x * 16 + tx;                    // p3-quad coords (0..127)
  int Y = blockIdx.y * 16 + ty;
  int c = blockIdx.z;
  const float* ip = p2 + (size_t)c * 262144 + (size_t)(4 * Y) * 512 + 4 * X;
  f4 r0 = *(const f4*)(ip);
  f4 r1 = *(const f4*)(ip + 512);
  f4 r2 = *(const f4*)(ip + 1024);
  f4 r3 = *(const f4*)(ip + 1536);
  float a00 = 0.25f * (r0.x + r0.y + r1.x + r1.y);
  float a01 = 0.25f * (r0.z + r0.w + r1.z + r1.w);
  float a10 = 0.25f * (r2.x + r2.y + r3.x + r3.y);
  float a11 = 0.25f * (r2.z + r2.w + r3.z + r3.w);
  float* cp = p3 + (size_t)c * 65536 + (size_t)(2 * Y) * 256 + 2 * X;
  f2 u; u.x = a00; u.y = a01; *(f2*)cp = u;
  f2 v; v.x = a10; v.y = a11; *(f2*)(cp + 256) = v;
  float m = 0.25f * (a00 + a01 + a10 + a11);
  t4[ty][tx] = m;
  p4[((size_t)c * 128 + Y) * 128 + X] = m;
  __syncthreads();
  int tid = ty * 16 + tx;
  if (tid < 64) {
    int y = tid >> 3, x = tid & 7;
    float w = 0.25f * (t4[2*y][2*x] + t4[2*y][2*x+1] + t4[2*y+1][2*x] + t4[2*y+1][2*x+1]);
    p5[((size_t)c * 64 + blockIdx.y * 8 + y) * 64 + blockIdx.x * 8 + x] = w;
  }
}

// ---------------- K3: fused up-chains p3->U3, p4->U4, p5->U5 (512^2) --------
__device__ __forceinline__ void up_coords(int o, int n, int& i0, int& i1, float& w0) {
  int m = o >> 1;
  if (o & 1) { i0 = m; i1 = min(m + 1, n - 1); w0 = 0.75f; }
  else       { i0 = max(m - 1, 0); i1 = m;     w0 = 0.25f; }
}

__global__ __launch_bounds__(256) void upchain_k(const float* __restrict__ p3,
                                                 const float* __restrict__ p4,
                                                 const float* __restrict__ p5,
                                                 float* __restrict__ U3,
                                                 float* __restrict__ U4,
                                                 float* __restrict__ U5) {
  __shared__ float a[19][20];
  __shared__ float mid[34][35];
  int z = blockIdx.z, im = z / 3, ch = z - im * 3;   // grid (8,8,9)
  int X0 = blockIdx.x * 64, Y0 = blockIdx.y * 64;
  int tid = threadIdx.x;
  int bx1 = X0 / 4 - 1, by1 = Y0 / 4 - 1;
  int bx2 = X0 / 2 - 1, by2 = Y0 / 2 - 1;

  if (im == 2) {
    const float* s = p5 + ch * 4096;
    for (int j = tid; j < 18 * 18; j += 256) {
      int r = j / 18, cc = j % 18;
      int gy = min(max(by1 + r, 0), 127), gx = min(max(bx1 + cc, 0), 127);
      int r0, r1, c0, c1; float wy0, wx0;
      up_coords(gy, 64, r0, r1, wy0);
      up_coords(gx, 64, c0, c1, wx0);
      float wy1 = 1.f - wy0, wx1 = 1.f - wx0;
      a[r][cc] = wy0 * (wx0 * s[r0*64+c0] + wx1 * s[r0*64+c1])
               + wy1 * (wx0 * s[r1*64+c0] + wx1 * s[r1*64+c1]);
    }
    __syncthreads();
    for (int j = tid; j < 34 * 34; j += 256) {
      int r = j / 34, cc = j % 34;
      int gy = min(max(by2 + r, 0), 255), gx = min(max(bx2 + cc, 0), 255);
      int r0, r1, c0, c1; float wy0, wx0;
      up_coords(gy, 128, r0, r1, wy0);
      up_coords(gx, 128, c0, c1, wx0);
      float wy1 = 1.f - wy0, wx1 = 1.f - wx0;
      int a0 = r0 - by1, a1 = r1 - by1, b0 = c0 - bx1, b1 = c1 - bx1;
      mid[r][cc] = wy0 * (wx0 * a[a0][b0] + wx1 * a[a0][b1])
                 + wy1 * (wx0 * a[a1][b0] + wx1 * a[a1][b1]);
    }
    __syncthreads();
  } else if (im == 1) {
    const float* s = p4 + ch * 16384;
    for (int j = tid; j < 34 * 34; j += 256) {
      int r = j / 34, cc = j % 34;
      int gy = min(max(by2 + r, 0), 255), gx = min(max(bx2 + cc, 0), 255);
      int r0, r1, c0, c1; float wy0, wx0;
      up_coords(gy, 128, r0, r1, wy0);
      up_coords(gx, 128, c0, c1, wx0);
      float wy1 = 1.f - wy0, wx1 = 1.f - wx0;
      mid[r][cc] = wy0 * (wx0 * s[r0*128+c0] + wx1 * s[r0*128+c1])
                 + wy1 * (wx0 * s[r1*128+c0] + wx1 * s[r1*128+c1]);
    }
    __syncthreads();
  }

  float* dst = (im == 0) ? U3 : (im == 1) ? U4 : U5;
  const float* p3g = p3 + ch * 65536;
  int lx = tid & 63, lyb = tid >> 6;
#pragma unroll 4
  for (int rr = 0; rr < 16; ++rr) {
    int ly = lyb * 16 + rr;
    int x = X0 + lx, y = Y0 + ly;
    int r0, r1, c0, c1; float wy0, wx0;
    up_coords(y, 256, r0, r1, wy0);
    up_coords(x, 256, c0, c1, wx0);
    float wy1 = 1.f - wy0, wx1 = 1.f - wx0;
    float v;
    if (im == 0) {
      v = wy0 * (wx0 * p3g[r0*256+c0] + wx1 * p3g[r0*256+c1])
        + wy1 * (wx0 * p3g[r1*256+c0] + wx1 * p3g[r1*256+c1]);
    } else {
      int a0 = r0 - by2, a1 = r1 - by2, b0 = c0 - bx2, b1 = c1 - bx2;
      v = wy0 * (wx0 * mid[a0][b0] + wx1 * mid[a0][b1])
        + wy1 * (wx0 * mid[a1][b0] + wx1 * mid[a1][b1]);
    }
    dst[((size_t)ch * 512 + y) * 512 + x] = v;
  }
}

// ---------------- K4: classification pass (L + B per px) --------------------
__device__ __forceinline__ float calc_B(float dd, int L, const BP& bp) {
  float d = sqrtf(dd);
  float R = 18.75f / (d + 18.75f);
  float R2 = R * R;
  float cL = (L == 1) ? bp.cc[1] : (L == 2) ? bp.cc[2] : (L == 3) ? bp.cc[3] : bp.cc[4];
  float cm = (L == 1) ? bp.cc[0] : (L == 2) ? bp.cc[1] : (L == 3) ? bp.cc[2] : (L == 4) ? bp.cc[3] : bp.cc[4];
  float tsL = (L >= 5) ? 0.f : __expf(-cL * R2);
  float tsm = __expf(-cm * R2);
  return (0.5f - tsL) / (tsm - tsL + 1e-5f);
}

__global__ __launch_bounds__(256) void classify_k(const float* __restrict__ fixs, int nf,
                                                  unsigned* __restrict__ meta,
                                                  h8* __restrict__ Bbuf, BP bp) {
  int xs = blockIdx.x * 64 + threadIdx.x;   // 0..511 (4-px x-span)
  int yp = blockIdx.y * 4 + threadIdx.y;    // 0..1023 (2-px y-pair)
  int x0 = xs * 4, y0 = yp * 2;
  int span = yp * 512 + xs;

  float d2[2][4];
#pragma unroll
  for (int j = 0; j < 2; ++j)
#pragma unroll
    for (int i = 0; i < 4; ++i) d2[j][i] = 3.4e38f;
  for (int f = 0; f < nf; ++f) {
    float dx0 = (float)x0 - fixs[2 * f], dy0 = (float)y0 - fixs[2 * f + 1];
#pragma unroll
    for (int j = 0; j < 2; ++j) {
      float dy = dy0 + (float)j, dy2 = dy * dy;
#pragma unroll
      for (int i = 0; i < 4; ++i) {
        float dx = dx0 + (float)i;
        d2[j][i] = fminf(d2[j][i], dx * dx + dy2);
      }
    }
  }

  unsigned m = 0;
  h8 b;
#pragma unroll
  for (int j = 0; j < 2; ++j)
#pragma unroll
    for (int i = 0; i < 4; ++i) {
      float dd = d2[j][i];
      int l = (dd >= bp.D2[0]) + (dd >= bp.D2[1]) + (dd >= bp.D2[2]) +
              (dd >= bp.D2[3]) + (dd >= bp.D2[4]);
      m |= (unsigned)l << (4 * (j * 4 + i));
      float B = (l == 0) ? 0.f : calc_B(dd, l, bp);
      b[j * 4 + i] = (_Float16)B;
    }
  meta[span] = m;
  Bbuf[span] = b;
}

// ---------------- single-channel samplers -----------------------------------
__device__ __forceinline__ void phase_one(const BP& bp, int ph, float w[3]) {
#pragma unroll
  for (int t = 0; t < 3; ++t)
    w[t] = (ph == 0) ? bp.P[0][t] : (ph == 1) ? bp.P[1][t] : (ph == 2) ? bp.P[2][t] : bp.P[3][t];
}

// sample one channel-plane of a 512^2 buffer for a 4x2 span
__device__ __forceinline__ void s2c(const float* __restrict__ b, int x0, int y0,
                                    const BP& bp, float o[2][4]) {
  int t = x0 >> 2, ky = y0 >> 2, yph = y0 & 3;
  int c[3], r[3];
#pragma unroll
  for (int j = 0; j < 3; ++j) {
    c[j] = min(max(t - 1 + j, 0), 511);
    r[j] = min(max(ky - 1 + j, 0), 511);
  }
  float v[3][3];
#pragma unroll
  for (int j = 0; j < 3; ++j) {
    const float* row = b + r[j] * 512;
    v[j][0] = row[c[0]]; v[j][1] = row[c[1]]; v[j][2] = row[c[2]];
  }
  const float* wr0 = bp.P[yph];
  const float* wr1 = bp.P[yph + 1];
  float rv0[3], rv1[3];
#pragma unroll
  for (int i = 0; i < 3; ++i) {
    rv0[i] = wr0[0] * v[0][i] + wr0[1] * v[1][i] + wr0[2] * v[2][i];
    rv1[i] = wr1[0] * v[0][i] + wr1[1] * v[1][i] + wr1[2] * v[2][i];
  }
#pragma unroll
  for (int p = 0; p < 4; ++p) {
    o[0][p] = bp.P[p][0] * rv0[0] + bp.P[p][1] * rv0[1] + bp.P[p][2] * rv0[2];
    o[1][p] = bp.P[p][0] * rv1[0] + bp.P[p][1] * rv1[1] + bp.P[p][2] * rv1[2];
  }
}

// sample one channel-plane of C1 (1024^2) for a 4x2 span
__device__ __forceinline__ void s1c(const float* __restrict__ b, int x0, int y0,
                                    float o[2][4]) {
  int q0 = x0 >> 1, qy = y0 >> 1;
  int c[4], r[3];
#pragma unroll
  for (int i = 0; i < 4; ++i) c[i] = min(max(q0 - 1 + i, 0), 1023);
#pragma unroll
  for (int j = 0; j < 3; ++j) r[j] = min(max(qy - 1 + j, 0), 1023);
  float v[3][4];
#pragma unroll
  for (int j = 0; j < 3; ++j) {
    const float* row = b + r[j] * 1024;
    v[j][0] = row[c[0]]; v[j][1] = row[c[1]]; v[j][2] = row[c[2]]; v[j][3] = row[c[3]];
  }
  float rv0[4], rv1[4];
#pragma unroll
  for (int i = 0; i < 4; ++i) {
    rv0[i] = 0.25f * v[0][i] + 0.75f * v[1][i];
    rv1[i] = 0.75f * v[1][i] + 0.25f * v[2][i];
  }
  o[0][0] = 0.25f * rv0[0] + 0.75f * rv0[1];
  o[0][1] = 0.75f * rv0[1] + 0.25f * rv0[2];
  o[0][2] = 0.25f * rv0[1] + 0.75f * rv0[2];
  o[0][3] = 0.75f * rv0[2] + 0.25f * rv0[3];
  o[1][0] = 0.25f * rv1[0] + 0.75f * rv1[1];
  o[1][1] = 0.75f * rv1[1] + 0.25f * rv1[2];
  o[1][2] = 0.25f * rv1[1] + 0.75f * rv1[2];
  o[1][3] = 0.75f * rv1[2] + 0.25f * rv1[3];
}

// per-pixel single-channel sampler (mixed spans only)
__device__ float sample_pxc(int level, int x, int y,
                            const float* __restrict__ imgc, const float* __restrict__ C1c,
                            const float* __restrict__ b2, const float* __restrict__ b3,
                            const float* __restrict__ b4, const float* __restrict__ b5,
                            const BP& bp) {
  if (level == 0) return imgc[(size_t)y * 2048 + x];
  if (level == 1) {
    int r0, r1, c0, c1; float wy0, wx0;
    up_coords(y, 1024, r0, r1, wy0);
    up_coords(x, 1024, c0, c1, wx0);
    float wy1 = 1.f - wy0, wx1 = 1.f - wx0;
    return wy0 * (wx0 * C1c[r0 * 1024 + c0] + wx1 * C1c[r0 * 1024 + c1])
         + wy1 * (wx0 * C1c[r1 * 1024 + c0] + wx1 * C1c[r1 * 1024 + c1]);
  }
  const float* buf = (level == 2) ? b2 : (level == 3) ? b3 : (level == 4) ? b4 : b5;
  int ky = y >> 2, kx = x >> 2;
  float wr[3], wc[3];
  phase_one(bp, y & 3, wr);
  phase_one(bp, x & 3, wc);
  float acc = 0.f;
#pragma unroll
  for (int j = 0; j < 3; ++j) {
    int r = min(max(ky - 1 + j, 0), 511);
    const float* row = buf + r * 512;
    float cs = 0.f;
#pragma unroll
    for (int i = 0; i < 3; ++i) {
      int cidx = min(max(kx - 1 + i, 0), 511);
      cs += wc[i] * row[cidx];
    }
    acc += wr[j] * cs;
  }
  return acc;
}

// ---------------- K5: per-channel blend -------------------------------------
__global__ __launch_bounds__(256) void blendc_k(
    const float* __restrict__ img, const float* __restrict__ C1,
    const float* __restrict__ B2, const float* __restrict__ B3,
    const float* __restrict__ B4, const float* __restrict__ B5,
    const unsigned* __restrict__ meta, const h8* __restrict__ Bbuf,
    float* __restrict__ out, BP bp) {
  int xs = blockIdx.x * 64 + threadIdx.x;   // 0..511
  int yp = blockIdx.y * 4 + threadIdx.y;    // 0..1023
  int ch = blockIdx.z;
  int x0 = xs * 4, y0 = yp * 2;
  int span = yp * 512 + xs;
  size_t ob = (size_t)ch * HW2048 + (size_t)y0 * 2048 + x0;
  const float* imgc = img + (size_t)ch * HW2048;

  unsigned m = meta[span];

  if (m == 0u) {   // pure As[0] = img copy
    f4 v0 = *(const f4*)(imgc + (size_t)y0 * 2048 + x0);
    f4 v1 = *(const f4*)(imgc + (size_t)(y0 + 1) * 2048 + x0);
    __builtin_nontemporal_store(v0, (f4*)(out + ob));
    __builtin_nontemporal_store(v1, (f4*)(out + ob + 2048));
    return;
  }

  h8 bh = Bbuf[span];
  const float* C1c = C1 + (size_t)ch * 1048576;
  const float* b2 = B2 + (size_t)ch * 262144;
  const float* b3 = B3 + (size_t)ch * 262144;
  const float* b4 = B4 + (size_t)ch * 262144;
  const float* b5 = B5 + (size_t)ch * 262144;

  unsigned l0 = m & 15u;
  float res[2][4];

  if (m == l0 * 0x11111111u) {   // uniform-L span
    float hi[2][4], lo[2][4];
    if (l0 == 1) {
      s1c(C1c, x0, y0, hi);
      f4 v0 = *(const f4*)(imgc + (size_t)y0 * 2048 + x0);
      f4 v1 = *(const f4*)(imgc + (size_t)(y0 + 1) * 2048 + x0);
      lo[0][0] = v0.x; lo[0][1] = v0.y; lo[0][2] = v0.z; lo[0][3] = v0.w;
      lo[1][0] = v1.x; lo[1][1] = v1.y; lo[1][2] = v1.z; lo[1][3] = v1.w;
    } else {
      const float* hb = (l0 == 2) ? b2 : (l0 == 3) ? b3 : (l0 == 4) ? b4 : b5;
      s2c(hb, x0, y0, bp, hi);
      if (l0 == 2) s1c(C1c, x0, y0, lo);
      else {
        const float* lb = (l0 == 3) ? b2 : (l0 == 4) ? b3 : b4;
        s2c(lb, x0, y0, bp, lo);
      }
    }
#pragma unroll
    for (int j = 0; j < 2; ++j)
#pragma unroll
      for (int i = 0; i < 4; ++i) {
        float B = (float)bh[j * 4 + i];
        res[j][i] = B * lo[j][i] + (1.f - B) * hi[j][i];
      }
  } else {
    // mixed-L span: per-pixel path
#pragma unroll
    for (int j = 0; j < 2; ++j)
#pragma unroll
      for (int i = 0; i < 4; ++i) {
        int l = (int)((m >> (4 * (j * 4 + i))) & 15u);
        int px = x0 + i, py = y0 + j;
        if (l == 0) {
          res[j][i] = imgc[(size_t)py * 2048 + px];
        } else {
          float B = (float)bh[j * 4 + i];
          float hi = sample_pxc(l,     px, py, imgc, C1c, b2, b3, b4, b5, bp);
          float lo = sample_pxc(l - 1, px, py, imgc, C1c, b2, b3, b4, b5, bp);
          res[j][i] = B * lo + (1.f - B) * hi;
        }
      }
  }

  f4 v0, v1;
  v0.x = res[0][0]; v0.y = res[0][1]; v0.z = res[0][2]; v0.w = res[0][3];
  v1.x = res[1][0]; v1.y = res[1][1]; v1.z = res[1][2]; v1.w = res[1][3];
  __builtin_nontemporal_store(v0, (f4*)(out + ob));
  __builtin_nontemporal_store(v1, (f4*)(out + ob + 2048));
}

extern "C" void kernel_launch(void* const* d_in, const int* in_sizes, int n_in,
                              void* d_out, int out_size, void* d_ws, size_t ws_size,
                              hipStream_t stream) {
  const float* img  = (const float*)d_in[0];
  const float* fixs = (const float*)d_in[1];
  int nf = in_sizes[1] / 2;
  float* out = (float*)d_out;
  float* ws  = (float*)d_ws;

  BP bp;
  const double sig = 0.248, Kd = 3.0, Pd = 7.5, Ad = 2.5;
  double obv = sqrt(log(2.0) / Kd) * sig;
  for (int j = 0; j < 5; ++j) {
    double om = obv * pow(2.0, 2 - j);
    double Dj = Pd * Ad * (1.0 / om - 1.0);
    bp.D2[j] = (float)(Dj * Dj);
  }
  for (int X = 0; X < 5; ++X)
    bp.cc[X] = (float)(Kd * pow(2.0, 2.0 * (X - 2)) / (sig * sig));
  const float Pt[4][3] = {{0.375f, 0.625f, 0.f},
                          {0.1875f, 0.75f, 0.0625f},
                          {0.0625f, 0.75f, 0.1875f},
                          {0.f, 0.625f, 0.375f}};
  for (int a = 0; a < 4; ++a) for (int t = 0; t < 3; ++t) bp.P[a][t] = Pt[a][t];

  size_t o = 0;
  float* C1 = ws + o; o += 3ull * 1024 * 1024;
  float* p2 = ws + o; o += 3ull * 512 * 512;
  float* p3 = ws + o; o += 3ull * 256 * 256;
  float* p4 = ws + o; o += 3ull * 128 * 128;
  float* p5 = ws + o; o += 3ull * 64 * 64;
  float* U3 = ws + o; o += 3ull * 512 * 512;
  float* U4 = ws + o; o += 3ull * 512 * 512;
  float* U5 = ws + o; o += 3ull * 512 * 512;
  unsigned* meta = (unsigned*)(ws + o); o += 512ull * 1024;
  h8* Bbuf = (h8*)(ws + o); o += 4ull * 512 * 1024;   // 16 B per span

  down12_k  <<<dim3(32, 32, 3), dim3(16, 16), 0, stream>>>(img, C1, p2);
  down345_k <<<dim3(8, 8, 3),   dim3(16, 16), 0, stream>>>(p2, p3, p4, p5);
  upchain_k <<<dim3(8, 8, 9),   dim3(256),    0, stream>>>(p3, p4, p5, U3, U4, U5);
  classify_k<<<dim3(8, 256),    dim3(64, 4),  0, stream>>>(fixs, nf, meta, Bbuf, bp);
  blendc_k  <<<dim3(8, 256, 3), dim3(64, 4),  0, stream>>>(img, C1, p2, U3, U4, U5,
                                                           meta, Bbuf, out, bp);
}